// Round 25
// baseline (1030.952 us; speedup 1.0000x reference)
//
#include <hip/hip_runtime.h>
#include <cstdint>
#include <cstddef>

// ---------------------------------------------------------------------------
// Graphormer-ish encoder forward, MI355X (gfx950).
// Round 24: attn 128 q-rows per block (grid 384 = b x 4 x h). Row-set B
// reuses row-set A's K/V fragment registers -> LDS reads, staging issues and
// barriers per FLOP halve. 32KB LDS unchanged; 384 blocks fully co-resident.
// GEMM config = round-17/21 verified optimum (unchanged).
// ---------------------------------------------------------------------------

typedef __attribute__((ext_vector_type(8))) short bf16x8;
typedef __attribute__((ext_vector_type(4))) short bf16x4;
typedef __attribute__((ext_vector_type(4))) float f32x4;
typedef __attribute__((ext_vector_type(4))) unsigned int u32x4;

static constexpr int D    = 768;
static constexpr int H    = 12;
static constexpr int S    = 512;
static constexpr int NN   = 511;
static constexpr int B    = 8;
static constexpr int FFN  = 3072;
static constexpr int ROWS = B * S;   // 4096

__device__ __forceinline__ short f2b(float x) {
    union { float f; uint32_t u; } c; c.f = x;
    uint32_t r = (c.u + 0x7fffu + ((c.u >> 16) & 1u)) >> 16;  // RNE
    return (short)(uint16_t)r;
}
__device__ __forceinline__ float b2f_lo(uint32_t u) {
    union { uint32_t u; float f; } c; c.u = u << 16; return c.f;
}
__device__ __forceinline__ float b2f_hi(uint32_t u) {
    union { uint32_t u; float f; } c; c.u = u & 0xffff0000u; return c.f;
}
__device__ __forceinline__ float gelu_f(float x) {
    return 0.5f * x * (1.0f + erff(x * 0.7071067811865476f));
}
__device__ __forceinline__ void gload16(const void* g, void* l) {
    __builtin_amdgcn_global_load_lds(
        (const __attribute__((address_space(1))) void*)g,
        (__attribute__((address_space(3))) void*)l, 16, 0, 0);
}

// PV MFMA: 16x16x16 bf16 (builtin -> compiler handles MFMA hazards).
#if __has_builtin(__builtin_amdgcn_mfma_f32_16x16x16bf16_1k)
__device__ __forceinline__ f32x4 mfma16(bf16x4 a, bf16x4 b, f32x4 c) {
    return __builtin_amdgcn_mfma_f32_16x16x16bf16_1k(a, b, c, 0, 0, 0);
}
__device__ __forceinline__ void mfma16_fence(f32x4* o) { (void)o; }
#else
__device__ __forceinline__ f32x4 mfma16(bf16x4 a, bf16x4 b, f32x4 c) {
    asm volatile("s_nop 1\n\tv_mfma_f32_16x16x16_bf16 %0, %1, %2, %0"
                 : "+v"(c) : "v"(a), "v"(b));
    return c;
}
__device__ __forceinline__ void mfma16_fence(f32x4* o) {
    asm volatile("s_nop 7\n\ts_nop 7"
                 : "+v"(o[0]), "+v"(o[1]), "+v"(o[2]), "+v"(o[3]));
}
#endif

// ---------------------------------------------------------------------------
__global__ __launch_bounds__(256) void embed_kernel(
    const int* __restrict__ x, const float* __restrict__ emb,
    const float* __restrict__ gtok, float* __restrict__ h)
{
    int row = blockIdx.x;
    int b = row >> 9, s = row & (S - 1);
    const float* src = (s == 0) ? gtok : (emb + (size_t)x[b * NN + (s - 1)] * D);
    float* dst = h + (size_t)row * D;
    int t = threadIdx.x;
    dst[t]       = src[t];
    dst[t + 256] = src[t + 256];
    dst[t + 512] = src[t + 512];
}

// ---------------------------------------------------------------------------
__global__ void ac_kernel(const float* __restrict__ w1, const float* __restrict__ b1,
                          const float* __restrict__ w2, const float* __restrict__ b2,
                          float* __restrict__ ac)
{
    int h = threadIdx.x;
    if (h < H) {
        float a = 0.f, c = 0.f;
        for (int k = 0; k < 128; ++k) { a += w1[k] * w2[k * H + h]; c += b1[k] * w2[k * H + h]; }
        ac[h] = a; ac[16 + h] = c + b2[h];
    }
}

// ---------------------------------------------------------------------------
// Bias pack, [b][i][j] layout: pb[b,i,j] = u32( bf16(2*ab) | bf16(sp)<<16 )
// ---------------------------------------------------------------------------
__global__ __launch_bounds__(256) void bias_pack_kernel(
    const float* __restrict__ ab, const float* __restrict__ sp,
    uint32_t* __restrict__ pb)
{
    int row = blockIdx.x;                 // b*S + i
    int b = row >> 9, i = row & 511;
    const float* abr = ab + (size_t)row * S;
    const float* spr = sp + ((size_t)b * NN + (i - 1)) * NN;
    uint32_t* out = pb + (size_t)row * S;
    #pragma unroll
    for (int jt = 0; jt < 2; ++jt) {
        int j = jt * 256 + threadIdx.x;
        float a2 = 2.f * abr[j];
        float spv = (i > 0 && j > 0) ? spr[j - 1] : 0.f;
        out[j] = (uint32_t)(uint16_t)f2b(a2) | ((uint32_t)(uint16_t)f2b(spv) << 16);
    }
}

// ---------------------------------------------------------------------------
// Per-layer weight convert+transpose: f32 [R][C] -> bf16 [C][R].
// ---------------------------------------------------------------------------
__global__ __launch_bounds__(256) void wcvt_kernel(
    const float* __restrict__ wq, const float* __restrict__ wk,
    const float* __restrict__ wv, const float* __restrict__ wo,
    const float* __restrict__ f1, const float* __restrict__ f2,
    short* __restrict__ wqkvT, short* __restrict__ woT,
    short* __restrict__ f1T, short* __restrict__ f2T)
{
    int t = blockIdx.x;
    const float* in; short* out; int R, C, tr, tc;
    if (t < 432) {
        int which = t / 144, tt = t - which * 144;
        in = (which == 0) ? wq : ((which == 1) ? wk : wv);
        out = wqkvT + (size_t)which * 768 * 768;
        R = 768; C = 768; tr = tt / 12; tc = tt % 12;
    } else if (t < 576) {
        int tt = t - 432; in = wo; out = woT; R = 768; C = 768; tr = tt / 12; tc = tt % 12;
    } else if (t < 1152) {
        int tt = t - 576; in = f1; out = f1T; R = 768; C = 3072; tr = tt / 48; tc = tt % 48;
    } else {
        int tt = t - 1152; in = f2; out = f2T; R = 3072; C = 768; tr = tt / 12; tc = tt % 12;
    }
    int r0 = tr * 64, c0 = tc * 64;
    __shared__ short tile[64][65];
    int tid = threadIdx.x;
    #pragma unroll
    for (int i = 0; i < 16; ++i) {
        int e = i * 256 + tid; int r = e >> 6, c = e & 63;
        tile[r][c] = f2b(in[(size_t)(r0 + r) * C + c0 + c]);
    }
    __syncthreads();
    #pragma unroll
    for (int i = 0; i < 16; ++i) {
        int e = i * 256 + tid; int c = e >> 6, r = e & 63;
        out[(size_t)(c0 + c) * R + r0 + r] = tile[r][c];
    }
}

// ---------------------------------------------------------------------------
__global__ __launch_bounds__(256) void ln_kernel(
    const float* __restrict__ in, const float* __restrict__ sc,
    const float* __restrict__ bi, float* __restrict__ outF,
    short* __restrict__ outB)
{
    int row = blockIdx.x, t = threadIdx.x;
    const float* x = in + (size_t)row * D;
    float e0 = x[t], e1 = x[t + 256], e2 = x[t + 512];
    float s  = e0 + e1 + e2;
    float sq = e0 * e0 + e1 * e1 + e2 * e2;
    #pragma unroll
    for (int off = 1; off < 64; off <<= 1) { s += __shfl_xor(s, off); sq += __shfl_xor(sq, off); }
    __shared__ float red[8];
    int w = t >> 6, lane = t & 63;
    if (lane == 0) { red[w] = s; red[4 + w] = sq; }
    __syncthreads();
    s  = red[0] + red[1] + red[2] + red[3];
    sq = red[4] + red[5] + red[6] + red[7];
    float m   = s * (1.f / D);
    float inv = rsqrtf(sq * (1.f / D) - m * m + 1e-5f);
    float v0 = (e0 - m) * inv * sc[t]       + bi[t];
    float v1 = (e1 - m) * inv * sc[t + 256] + bi[t + 256];
    float v2 = (e2 - m) * inv * sc[t + 512] + bi[t + 512];
    if (outB) {
        short* o = outB + (size_t)row * D;
        o[t] = f2b(v0); o[t + 256] = f2b(v1); o[t + 512] = f2b(v2);
    } else {
        float* o = outF + (size_t)row * D;
        o[t] = v0; o[t + 256] = v1; o[t + 512] = v2;
    }
}

// ---------------------------------------------------------------------------
// bf16 MFMA GEMM, BM x BN x BK tile, depth-2 pipeline (3 LDS bufs, counted
// vmcnt + raw s_barrier). Swizzle both-sides: BK=32: chunk ^= (r>>1)&3;
// BK=64: chunk ^= r&7. NFAST: tile decode N-fastest within XCD chunk.
// ---------------------------------------------------------------------------
template<int BM, int BN, int BK, bool NFAST>
__global__ __launch_bounds__(256) void gemm2(
    const short* __restrict__ A, const short* __restrict__ Wt,
    const float* __restrict__ Bb0, const float* __restrict__ Bb1, const float* __restrict__ Bb2,
    float* __restrict__ outF, const float* __restrict__ resid,
    short* __restrict__ outB,
    int K, int nper, int gx, float alpha0, int mode)
{
    constexpr int MR = BM / 32;
    constexpr int NR = BN / 32;
    constexpr int SUBK = BK / 32;
    constexpr int AU = BM * BK / 2048;       // stage iters for A
    constexpr int BU = BN * BK / 2048;
    constexpr int CH = BK / 8;               // 16B chunks per row
    constexpr int NL = AU + BU;              // per-thread loads per tile
    __shared__ __align__(16) short As[3][BM * BK];
    __shared__ __align__(16) short Bs[3][BN * BK];
    int tid  = threadIdx.x;
    int lane = tid & 63;
    int w    = tid >> 6;

    int nwg = gridDim.x;
    int bid = blockIdx.x;
    int sid = (bid & 7) * (nwg >> 3) + (bid >> 3);
    int row0, n0;
    if (NFAST) { row0 = (sid / gx) * BM; n0 = (sid % gx) * BN; }
    else       { row0 = (sid % gx) * BM; n0 = (sid / gx) * BN; }

    int which = n0 / nper;
    int ncol0 = n0 - which * nper;
    const float* Bv = (which == 0) ? Bb0 : ((which == 1) ? Bb1 : Bb2);
    float alpha = (which == 0) ? alpha0 : 1.0f;

    int wr = (w >> 1) * (BM / 2);
    int wc = (w & 1) * (BN / 2);
    int fr = lane & 15;
    int q4 = lane >> 4;          // 0..3

    auto swz = [&](int r) -> int { return (BK == 64) ? (r & 7) : ((r >> 1) & 3); };

    f32x4 acc[MR][NR] = {};

    auto stageA = [&](int buf, int k0) {
        #pragma unroll
        for (int ii = 0; ii < AU; ++ii) {
            int U = ii * 256 + tid;          // 16B unit
            int r = U / CH;
            int ch = (U % CH) ^ swz(r);
            gload16(A + (size_t)(row0 + r) * K + k0 + ch * 8,
                    (char*)&As[buf][0] + ((size_t)ii * 256 + w * 64) * 16);
        }
    };
    auto stageB = [&](int buf, int k0) {
        #pragma unroll
        for (int ii = 0; ii < BU; ++ii) {
            int U = ii * 256 + tid;
            int r = U / CH;
            int ch = (U % CH) ^ swz(r);
            gload16(Wt + (size_t)(n0 + r) * K + k0 + ch * 8,
                    (char*)&Bs[buf][0] + ((size_t)ii * 256 + w * 64) * 16);
        }
    };
    auto compute = [&](int buf) {
        #pragma unroll
        for (int s = 0; s < SUBK; ++s) {
            bf16x8 af[MR], bfr[NR];
            #pragma unroll
            for (int m = 0; m < MR; ++m) {
                int r = wr + m * 16 + fr;
                af[m] = *(const bf16x8*)((const char*)&As[buf][0]
                        + (size_t)r * (2 * BK) + (((q4 + 4 * s) ^ swz(r)) * 16));
            }
            #pragma unroll
            for (int n = 0; n < NR; ++n) {
                int r = wc + n * 16 + fr;
                bfr[n] = *(const bf16x8*)((const char*)&Bs[buf][0]
                        + (size_t)r * (2 * BK) + (((q4 + 4 * s) ^ swz(r)) * 16));
            }
            #pragma unroll
            for (int m = 0; m < MR; ++m)
                #pragma unroll
                for (int n = 0; n < NR; ++n)
                    acc[m][n] = __builtin_amdgcn_mfma_f32_16x16x32_bf16(af[m], bfr[n], acc[m][n], 0, 0, 0);
        }
    };

    int nt = K / BK;
    stageA(0, 0); stageB(0, 0);
    stageA(1, BK); stageB(1, BK);
    for (int t = 0; t < nt - 1; ++t) {
        asm volatile("s_waitcnt vmcnt(%0)" :: "i"(NL) : "memory");   // tile t landed
        __builtin_amdgcn_sched_barrier(0);
        __builtin_amdgcn_s_barrier();
        if (t + 2 < nt) {
            int b2 = (t + 2) % 3;
            stageA(b2, (t + 2) * BK);
            stageB(b2, (t + 2) * BK);
        }
        compute(t % 3);
    }
    asm volatile("s_waitcnt vmcnt(0)" ::: "memory");
    __builtin_amdgcn_sched_barrier(0);
    __builtin_amdgcn_s_barrier();
    compute((nt - 1) % 3);

    int rr = q4 * 4;
    if (mode == 1) {
        short* base = outB + (size_t)which * ROWS * D;
        #pragma unroll
        for (int m = 0; m < MR; ++m) {
            int rowb = row0 + wr + m * 16 + rr;
            int b2 = rowb >> 9, s0 = rowb & 511;
            #pragma unroll
            for (int n = 0; n < NR; ++n) {
                int col = ncol0 + wc + n * 16 + fr;
                int h2 = col >> 6, d2 = col & 63;
                float bv = Bv[col];
                if (which == 2) {
                    bf16x4 pk;
                    #pragma unroll
                    for (int ri = 0; ri < 4; ++ri) pk[ri] = f2b(acc[m][n][ri] + bv);
                    *(bf16x4*)&base[(((size_t)b2 * H + h2) * 64 + d2) * 512 + s0] = pk;
                } else {
                    #pragma unroll
                    for (int ri = 0; ri < 4; ++ri)
                        base[(((size_t)b2 * H + h2) * 512 + (s0 + ri)) * 64 + d2] =
                            f2b((acc[m][n][ri] + bv) * alpha);
                }
            }
        }
        return;
    }

    #pragma unroll
    for (int m = 0; m < MR; ++m) {
        #pragma unroll
        for (int n = 0; n < NR; ++n) {
            int col  = ncol0 + wc + n * 16 + fr;
            float bv = Bv[col];
            #pragma unroll
            for (int ri = 0; ri < 4; ++ri) {
                int row = row0 + wr + m * 16 + rr + ri;
                size_t idx = (size_t)row * nper + col;
                float val = acc[m][n][ri] + bv;
                if (mode == 2) {
                    outB[idx] = f2b(gelu_f(val));
                } else {
                    outF[idx] = val + resid[idx];
                }
            }
        }
    }
}

// ---------------------------------------------------------------------------
// LDS-staged online-softmax attention, 128 q-rows/block (2 row sets A/B
// sharing K/V fragment registers), KV j-tile = 64 (32KB LDS).
// Grid: 384 = b(8) x qblk(4) x h(12).
// ---------------------------------------------------------------------------
__global__ __launch_bounds__(256) void attn_kernel(
    const short* __restrict__ qb, const short* __restrict__ kbuf,
    const short* __restrict__ vtb,
    const uint32_t* __restrict__ pb,
    const float* __restrict__ vd, const float* __restrict__ ac,
    short* __restrict__ o)
{
    __shared__ __align__(16) short Ks[2][64 * 64];   // 8KB each: [j-row][d]
    __shared__ __align__(16) short Vs[2][64 * 64];   // 8KB each: [d][j]
    int tid = threadIdx.x, lane = tid & 63, w = tid >> 6;
    int bid = blockIdx.x;
    int b    = bid & 7;
    int qblk = (bid >> 3) & 3;
    int hh   = bid >> 5;
    int fr = lane & 15, g16 = lane >> 4;
    int kb8 = g16 * 8, rr = g16 * 4;
    int i0A = qblk * 128 + w * 16;
    int i0B = i0A + 64;
    int iA  = i0A + fr;
    int iB  = i0B + fr;

    const short* qp = qb   + ((size_t)(b * H + hh) * S) * 64;
    const short* kp = kbuf + ((size_t)(b * H + hh) * S) * 64;
    const short* vp = vtb  + ((size_t)(b * H + hh) * 64) * S;

    bf16x8 aqA0 = *(const bf16x8*)&qp[(i0A + fr) * 64 + kb8];
    bf16x8 aqA1 = *(const bf16x8*)&qp[(i0A + fr) * 64 + 32 + kb8];
    bf16x8 aqB0 = *(const bf16x8*)&qp[(i0B + fr) * 64 + kb8];
    bf16x8 aqB1 = *(const bf16x8*)&qp[(i0B + fr) * 64 + 32 + kb8];

    float Ah = ac[hh], Ch = ac[16 + hh], th = vd[hh];
    const uint32_t* pbbA = pb + (size_t)b * S * S + (size_t)iA * S;
    const uint32_t* pbbB = pb + (size_t)b * S * S + (size_t)iB * S;

    auto stageK = [&](int buf, int j0) {
        #pragma unroll
        for (int ii = 0; ii < 2; ++ii) {
            int U = ii * 256 + tid;
            int r = U >> 3;
            int ch = (U & 7) ^ (r & 7);
            gload16(kp + (size_t)(j0 + r) * 64 + ch * 8,
                    (char*)&Ks[buf][0] + ((size_t)ii * 256 + w * 64) * 16);
        }
    };
    auto stageV = [&](int buf, int j0) {
        #pragma unroll
        for (int ii = 0; ii < 2; ++ii) {
            int U = ii * 256 + tid;
            int d = U >> 3;
            int s8 = (2 * (U & 7)) ^ (d & 14);
            gload16(vp + (size_t)d * S + j0 + s8 * 4,
                    (char*)&Vs[buf][0] + ((size_t)ii * 256 + w * 64) * 16);
        }
    };

    float mA = -3.0e38f, lA = 0.f;
    float mB = -3.0e38f, lB = 0.f;
    f32x4 oaccA[4] = {};
    f32x4 oaccB[4] = {};

    stageK(0, 0);
    stageV(0, 0);
    __syncthreads();
    int buf = 0;
    #pragma unroll 1
    for (int t = 0; t < 8; ++t) {
        if (t < 7) { stageK(buf ^ 1, (t + 1) * 64); stageV(buf ^ 1, (t + 1) * 64); }
        f32x4 sA[4], sB[4];
        #pragma unroll
        for (int jt = 0; jt < 4; ++jt) {
            int jb = t * 4 + jt;
            u32x4 uA = *(const u32x4*)&pbbA[jb * 16 + rr];
            u32x4 uB = *(const u32x4*)&pbbB[jb * 16 + rr];
            f32x4 cA, cB;
            #pragma unroll
            for (int ri = 0; ri < 4; ++ri) {
                int j = jb * 16 + rr + ri;
                float biasA = b2f_lo(uA[ri]);
                if (iA > 0 && j > 0) biasA += b2f_hi(uA[ri]) * Ah + Ch;
                if (iA == 0 || j == 0) biasA += th;
                cA[ri] = biasA;
                float biasB = b2f_lo(uB[ri]);
                if (j > 0) biasB += b2f_hi(uB[ri]) * Ah + Ch;   // iB >= 64 > 0 always
                if (j == 0) biasB += th;
                cB[ri] = biasB;
            }
            int r = jt * 16 + fr;
            const char* krow = (const char*)&Ks[buf][0] + r * 128;
            bf16x8 kf0 = *(const bf16x8*)(krow + ((g16 ^ (r & 7)) * 16));
            bf16x8 kf1 = *(const bf16x8*)(krow + (((g16 + 4) ^ (r & 7)) * 16));
            cA = __builtin_amdgcn_mfma_f32_16x16x32_bf16(kf0, aqA0, cA, 0, 0, 0);
            sA[jt] = __builtin_amdgcn_mfma_f32_16x16x32_bf16(kf1, aqA1, cA, 0, 0, 0);
            cB = __builtin_amdgcn_mfma_f32_16x16x32_bf16(kf0, aqB0, cB, 0, 0, 0);
            sB[jt] = __builtin_amdgcn_mfma_f32_16x16x32_bf16(kf1, aqB1, cB, 0, 0, 0);
        }
        // --- softmax row set A ---
        {
            float tm = sA[0][0];
            #pragma unroll
            for (int jt = 0; jt < 4; ++jt)
                #pragma unroll
                for (int ri = 0; ri < 4; ++ri) tm = fmaxf(tm, sA[jt][ri]);
            tm = fmaxf(tm, __shfl_xor(tm, 16));
            tm = fmaxf(tm, __shfl_xor(tm, 32));
            float mnew = fmaxf(mA, tm);
            float scale = __expf(mA - mnew);
            lA *= scale;
            #pragma unroll
            for (int ri = 0; ri < 4; ++ri) {
                float scr = __shfl(scale, rr + ri);
                #pragma unroll
                for (int dt = 0; dt < 4; ++dt) oaccA[dt][ri] *= scr;
            }
            #pragma unroll
            for (int jt = 0; jt < 4; ++jt)
                #pragma unroll
                for (int ri = 0; ri < 4; ++ri) {
                    float p = __expf(sA[jt][ri] - mnew);
                    sA[jt][ri] = p;
                    lA += p;
                }
            mA = mnew;
        }
        // --- softmax row set B ---
        {
            float tm = sB[0][0];
            #pragma unroll
            for (int jt = 0; jt < 4; ++jt)
                #pragma unroll
                for (int ri = 0; ri < 4; ++ri) tm = fmaxf(tm, sB[jt][ri]);
            tm = fmaxf(tm, __shfl_xor(tm, 16));
            tm = fmaxf(tm, __shfl_xor(tm, 32));
            float mnew = fmaxf(mB, tm);
            float scale = __expf(mB - mnew);
            lB *= scale;
            #pragma unroll
            for (int ri = 0; ri < 4; ++ri) {
                float scr = __shfl(scale, rr + ri);
                #pragma unroll
                for (int dt = 0; dt < 4; ++dt) oaccB[dt][ri] *= scr;
            }
            #pragma unroll
            for (int jt = 0; jt < 4; ++jt)
                #pragma unroll
                for (int ri = 0; ri < 4; ++ri) {
                    float p = __expf(sB[jt][ri] - mnew);
                    sB[jt][ri] = p;
                    lB += p;
                }
            mB = mnew;
        }
        // --- PV: shared V fragments feed both row sets ---
        #pragma unroll
        for (int jt = 0; jt < 4; ++jt) {
            bf16x4 paA, paB;
            #pragma unroll
            for (int ri = 0; ri < 4; ++ri) { paA[ri] = f2b(sA[jt][ri]); paB[ri] = f2b(sB[jt][ri]); }
            #pragma unroll
            for (int dt = 0; dt < 4; ++dt) {
                int d = dt * 16 + fr;
                const char* vrow = (const char*)&Vs[buf][0] + d * 128;
                bf16x4 vb = *(const bf16x4*)(vrow + (((jt * 4 + g16) ^ (d & 14)) * 8));
                oaccA[dt] = mfma16(paA, vb, oaccA[dt]);
                oaccB[dt] = mfma16(paB, vb, oaccB[dt]);
            }
        }
        __syncthreads();
        buf ^= 1;
    }
    mfma16_fence(oaccA);
    mfma16_fence(oaccB);

    lA += __shfl_xor(lA, 16);
    lA += __shfl_xor(lA, 32);
    lB += __shfl_xor(lB, 16);
    lB += __shfl_xor(lB, 32);
    float invlA = 1.f / lA;
    float invlB = 1.f / lB;
    #pragma unroll
    for (int ri = 0; ri < 4; ++ri) {
        float ivA = __shfl(invlA, rr + ri);
        float ivB = __shfl(invlB, rr + ri);
        #pragma unroll
        for (int dt = 0; dt < 4; ++dt) {
            o[((size_t)(b * S + i0A + rr + ri) * H + hh) * 64 + dt * 16 + fr] =
                f2b(oaccA[dt][ri] * ivA);
            o[((size_t)(b * S + i0B + rr + ri) * H + hh) * 64 + dt * 16 + fr] =
                f2b(oaccB[dt][ri] * ivB);
        }
    }
}

// ---------------------------------------------------------------------------
extern "C" void kernel_launch(void* const* d_in, const int* in_sizes, int n_in,
                              void* d_out, int out_size, void* d_ws, size_t ws_size,
                              hipStream_t stream)
{
    const float* attn_bias   = (const float*)d_in[0];
    const float* spatial_pos = (const float*)d_in[1];
    const int*   xx          = (const int*)d_in[2];
    const float* node_emb    = (const float*)d_in[3];
    const float* graph_token = (const float*)d_in[4];
    const float* virt_dist   = (const float*)d_in[5];
    const float* sp_w1 = (const float*)d_in[6];
    const float* sp_b1 = (const float*)d_in[7];
    const float* sp_w2 = (const float*)d_in[8];
    const float* sp_b2 = (const float*)d_in[9];
    const float* ln1_s = (const float*)d_in[10];
    const float* ln1_b = (const float*)d_in[11];
    const float* wq = (const float*)d_in[12];
    const float* bq = (const float*)d_in[13];
    const float* wk = (const float*)d_in[14];
    const float* bk = (const float*)d_in[15];
    const float* wv = (const float*)d_in[16];
    const float* bv = (const float*)d_in[17];
    const float* wo = (const float*)d_in[18];
    const float* bo = (const float*)d_in[19];
    const float* ln2_s = (const float*)d_in[20];
    const float* ln2_b = (const float*)d_in[21];
    const float* fw1 = (const float*)d_in[22];
    const float* fb1 = (const float*)d_in[23];
    const float* fw2 = (const float*)d_in[24];
    const float* fb2 = (const float*)d_in[25];
    const float* fln_s = (const float*)d_in[26];
    const float* fln_b = (const float*)d_in[27];

    float* wsf = (float*)d_ws;
    const size_t SZ = (size_t)ROWS * D;        // 3,145,728
    float* h   = wsf;                          // f32 [ROWS][D]
    float* acb = wsf + SZ;                     // A[12],C[12]
    short* s16 = (short*)(wsf + SZ + 64);
    short* yob = s16;                          // bf16 [ROWS][D]
    short* g16b = s16 + SZ;                    // bf16 [ROWS][FFN]
    short* bfq = g16b + (size_t)ROWS * FFN;    // 3 x bf16 [ROWS*D]
    short* wqkvT = bfq + 3 * SZ;               // [2304][768]
    short* woT   = wqkvT + 2304 * 768;         // [768][768]
    short* f1T   = woT + 768 * 768;            // [3072][768]
    short* f2T   = f1T + (size_t)3072 * 768;   // [768][3072]
    uint32_t* pbias = (uint32_t*)(f2T + (size_t)768 * 3072);  // [B][S][S] u32

    embed_kernel<<<ROWS, 256, 0, stream>>>(xx, node_emb, graph_token, h);
    ac_kernel<<<1, 64, 0, stream>>>(sp_w1, sp_b1, sp_w2, sp_b2, acb);
    bias_pack_kernel<<<ROWS, 256, 0, stream>>>(attn_bias, spatial_pos, pbias);

    for (int l = 0; l < 6; ++l) {
        wcvt_kernel<<<1728, 256, 0, stream>>>(
            wq + (size_t)l * D * D, wk + (size_t)l * D * D, wv + (size_t)l * D * D,
            wo + (size_t)l * D * D, fw1 + (size_t)l * D * FFN, fw2 + (size_t)l * FFN * D,
            wqkvT, woT, f1T, f2T);
        ln_kernel<<<ROWS, 256, 0, stream>>>(h, ln1_s + l * D, ln1_b + l * D, nullptr, yob);
        // QKV: 128x128/BK=32, M-fastest; 576 blocks
        gemm2<128, 128, 32, false><<<576, 256, 0, stream>>>(
            yob, wqkvT, bq + l * D, bk + l * D, bv + l * D,
            nullptr, nullptr, bfq, D, D, 32, 0.125f, 1);
        // attn: 128 q-rows/block; 8 x 4 x 12 = 384 blocks
        attn_kernel<<<384, 256, 0, stream>>>(
            bfq, bfq + SZ, bfq + 2 * SZ, pbias, virt_dist, acb, yob);
        // o-proj: 64x64/BK=64, N-fastest; 768 blocks
        gemm2<64, 64, 64, true><<<768, 256, 0, stream>>>(
            yob, woT, bo + l * D, nullptr, nullptr,
            h, h, nullptr, D, D, 12, 1.0f, 0);
        ln_kernel<<<ROWS, 256, 0, stream>>>(h, ln2_s + l * D, ln2_b + l * D, nullptr, yob);
        // FFN1: 128x128/BK=32, M-fastest; 768 blocks
        gemm2<128, 128, 32, false><<<768, 256, 0, stream>>>(
            yob, f1T, fb1 + l * FFN, nullptr, nullptr,
            nullptr, nullptr, g16b, D, FFN, 32, 1.0f, 2);
        // FFN2: 64x64/BK=64, N-fastest; 768 blocks
        gemm2<64, 64, 64, true><<<768, 256, 0, stream>>>(
            g16b, f2T, fb2 + l * D, nullptr, nullptr,
            h, h, nullptr, FFN, D, 12, 1.0f, 0);
    }
    ln_kernel<<<ROWS, 256, 0, stream>>>(h, fln_s, fln_b, (float*)d_out, nullptr);
}

// Round 26
// 1002.612 us; speedup vs baseline: 1.0283x; 1.0283x over previous
//
#include <hip/hip_runtime.h>
#include <cstdint>
#include <cstddef>

// ---------------------------------------------------------------------------
// Graphormer-ish encoder forward, MI355X (gfx950).
// Round 25: final revert to the twice-verified optimum (1003.6 / 1009.1 us).
// - GEMMs: QKV/FFN1 = 128x128/BK32/M-fast (tile-level reuse);
//          FFN2/o-proj = 64x64/BK64/N-fast (residency + barrier density).
// - attn: 64 q-rows/block, KV j-tile 64 (32KB LDS, fully co-resident).
// Perturbations 18/19/20/22/24 all regressed; this is the local optimum.
// ---------------------------------------------------------------------------

typedef __attribute__((ext_vector_type(8))) short bf16x8;
typedef __attribute__((ext_vector_type(4))) short bf16x4;
typedef __attribute__((ext_vector_type(4))) float f32x4;
typedef __attribute__((ext_vector_type(4))) unsigned int u32x4;

static constexpr int D    = 768;
static constexpr int H    = 12;
static constexpr int S    = 512;
static constexpr int NN   = 511;
static constexpr int B    = 8;
static constexpr int FFN  = 3072;
static constexpr int ROWS = B * S;   // 4096

__device__ __forceinline__ short f2b(float x) {
    union { float f; uint32_t u; } c; c.f = x;
    uint32_t r = (c.u + 0x7fffu + ((c.u >> 16) & 1u)) >> 16;  // RNE
    return (short)(uint16_t)r;
}
__device__ __forceinline__ float b2f_lo(uint32_t u) {
    union { uint32_t u; float f; } c; c.u = u << 16; return c.f;
}
__device__ __forceinline__ float b2f_hi(uint32_t u) {
    union { uint32_t u; float f; } c; c.u = u & 0xffff0000u; return c.f;
}
__device__ __forceinline__ float gelu_f(float x) {
    return 0.5f * x * (1.0f + erff(x * 0.7071067811865476f));
}
__device__ __forceinline__ void gload16(const void* g, void* l) {
    __builtin_amdgcn_global_load_lds(
        (const __attribute__((address_space(1))) void*)g,
        (__attribute__((address_space(3))) void*)l, 16, 0, 0);
}

// PV MFMA: 16x16x16 bf16 (builtin -> compiler handles MFMA hazards).
#if __has_builtin(__builtin_amdgcn_mfma_f32_16x16x16bf16_1k)
__device__ __forceinline__ f32x4 mfma16(bf16x4 a, bf16x4 b, f32x4 c) {
    return __builtin_amdgcn_mfma_f32_16x16x16bf16_1k(a, b, c, 0, 0, 0);
}
__device__ __forceinline__ void mfma16_fence(f32x4* o) { (void)o; }
#else
__device__ __forceinline__ f32x4 mfma16(bf16x4 a, bf16x4 b, f32x4 c) {
    asm volatile("s_nop 1\n\tv_mfma_f32_16x16x16_bf16 %0, %1, %2, %0"
                 : "+v"(c) : "v"(a), "v"(b));
    return c;
}
__device__ __forceinline__ void mfma16_fence(f32x4* o) {
    asm volatile("s_nop 7\n\ts_nop 7"
                 : "+v"(o[0]), "+v"(o[1]), "+v"(o[2]), "+v"(o[3]));
}
#endif

// ---------------------------------------------------------------------------
__global__ __launch_bounds__(256) void embed_kernel(
    const int* __restrict__ x, const float* __restrict__ emb,
    const float* __restrict__ gtok, float* __restrict__ h)
{
    int row = blockIdx.x;
    int b = row >> 9, s = row & (S - 1);
    const float* src = (s == 0) ? gtok : (emb + (size_t)x[b * NN + (s - 1)] * D);
    float* dst = h + (size_t)row * D;
    int t = threadIdx.x;
    dst[t]       = src[t];
    dst[t + 256] = src[t + 256];
    dst[t + 512] = src[t + 512];
}

// ---------------------------------------------------------------------------
__global__ void ac_kernel(const float* __restrict__ w1, const float* __restrict__ b1,
                          const float* __restrict__ w2, const float* __restrict__ b2,
                          float* __restrict__ ac)
{
    int h = threadIdx.x;
    if (h < H) {
        float a = 0.f, c = 0.f;
        for (int k = 0; k < 128; ++k) { a += w1[k] * w2[k * H + h]; c += b1[k] * w2[k * H + h]; }
        ac[h] = a; ac[16 + h] = c + b2[h];
    }
}

// ---------------------------------------------------------------------------
// Bias pack, [b][i][j] layout: pb[b,i,j] = u32( bf16(2*ab) | bf16(sp)<<16 )
// ---------------------------------------------------------------------------
__global__ __launch_bounds__(256) void bias_pack_kernel(
    const float* __restrict__ ab, const float* __restrict__ sp,
    uint32_t* __restrict__ pb)
{
    int row = blockIdx.x;                 // b*S + i
    int b = row >> 9, i = row & 511;
    const float* abr = ab + (size_t)row * S;
    const float* spr = sp + ((size_t)b * NN + (i - 1)) * NN;
    uint32_t* out = pb + (size_t)row * S;
    #pragma unroll
    for (int jt = 0; jt < 2; ++jt) {
        int j = jt * 256 + threadIdx.x;
        float a2 = 2.f * abr[j];
        float spv = (i > 0 && j > 0) ? spr[j - 1] : 0.f;
        out[j] = (uint32_t)(uint16_t)f2b(a2) | ((uint32_t)(uint16_t)f2b(spv) << 16);
    }
}

// ---------------------------------------------------------------------------
// Per-layer weight convert+transpose: f32 [R][C] -> bf16 [C][R].
// ---------------------------------------------------------------------------
__global__ __launch_bounds__(256) void wcvt_kernel(
    const float* __restrict__ wq, const float* __restrict__ wk,
    const float* __restrict__ wv, const float* __restrict__ wo,
    const float* __restrict__ f1, const float* __restrict__ f2,
    short* __restrict__ wqkvT, short* __restrict__ woT,
    short* __restrict__ f1T, short* __restrict__ f2T)
{
    int t = blockIdx.x;
    const float* in; short* out; int R, C, tr, tc;
    if (t < 432) {
        int which = t / 144, tt = t - which * 144;
        in = (which == 0) ? wq : ((which == 1) ? wk : wv);
        out = wqkvT + (size_t)which * 768 * 768;
        R = 768; C = 768; tr = tt / 12; tc = tt % 12;
    } else if (t < 576) {
        int tt = t - 432; in = wo; out = woT; R = 768; C = 768; tr = tt / 12; tc = tt % 12;
    } else if (t < 1152) {
        int tt = t - 576; in = f1; out = f1T; R = 768; C = 3072; tr = tt / 48; tc = tt % 48;
    } else {
        int tt = t - 1152; in = f2; out = f2T; R = 3072; C = 768; tr = tt / 12; tc = tt % 12;
    }
    int r0 = tr * 64, c0 = tc * 64;
    __shared__ short tile[64][65];
    int tid = threadIdx.x;
    #pragma unroll
    for (int i = 0; i < 16; ++i) {
        int e = i * 256 + tid; int r = e >> 6, c = e & 63;
        tile[r][c] = f2b(in[(size_t)(r0 + r) * C + c0 + c]);
    }
    __syncthreads();
    #pragma unroll
    for (int i = 0; i < 16; ++i) {
        int e = i * 256 + tid; int c = e >> 6, r = e & 63;
        out[(size_t)(c0 + c) * R + r0 + r] = tile[r][c];
    }
}

// ---------------------------------------------------------------------------
__global__ __launch_bounds__(256) void ln_kernel(
    const float* __restrict__ in, const float* __restrict__ sc,
    const float* __restrict__ bi, float* __restrict__ outF,
    short* __restrict__ outB)
{
    int row = blockIdx.x, t = threadIdx.x;
    const float* x = in + (size_t)row * D;
    float e0 = x[t], e1 = x[t + 256], e2 = x[t + 512];
    float s  = e0 + e1 + e2;
    float sq = e0 * e0 + e1 * e1 + e2 * e2;
    #pragma unroll
    for (int off = 1; off < 64; off <<= 1) { s += __shfl_xor(s, off); sq += __shfl_xor(sq, off); }
    __shared__ float red[8];
    int w = t >> 6, lane = t & 63;
    if (lane == 0) { red[w] = s; red[4 + w] = sq; }
    __syncthreads();
    s  = red[0] + red[1] + red[2] + red[3];
    sq = red[4] + red[5] + red[6] + red[7];
    float m   = s * (1.f / D);
    float inv = rsqrtf(sq * (1.f / D) - m * m + 1e-5f);
    float v0 = (e0 - m) * inv * sc[t]       + bi[t];
    float v1 = (e1 - m) * inv * sc[t + 256] + bi[t + 256];
    float v2 = (e2 - m) * inv * sc[t + 512] + bi[t + 512];
    if (outB) {
        short* o = outB + (size_t)row * D;
        o[t] = f2b(v0); o[t + 256] = f2b(v1); o[t + 512] = f2b(v2);
    } else {
        float* o = outF + (size_t)row * D;
        o[t] = v0; o[t + 256] = v1; o[t + 512] = v2;
    }
}

// ---------------------------------------------------------------------------
// bf16 MFMA GEMM, BM x BN x BK tile, depth-2 pipeline (3 LDS bufs, counted
// vmcnt + raw s_barrier). Swizzle both-sides: BK=32: chunk ^= (r>>1)&3;
// BK=64: chunk ^= r&7. NFAST: tile decode N-fastest within XCD chunk.
// ---------------------------------------------------------------------------
template<int BM, int BN, int BK, bool NFAST>
__global__ __launch_bounds__(256) void gemm2(
    const short* __restrict__ A, const short* __restrict__ Wt,
    const float* __restrict__ Bb0, const float* __restrict__ Bb1, const float* __restrict__ Bb2,
    float* __restrict__ outF, const float* __restrict__ resid,
    short* __restrict__ outB,
    int K, int nper, int gx, float alpha0, int mode)
{
    constexpr int MR = BM / 32;
    constexpr int NR = BN / 32;
    constexpr int SUBK = BK / 32;
    constexpr int AU = BM * BK / 2048;       // stage iters for A
    constexpr int BU = BN * BK / 2048;
    constexpr int CH = BK / 8;               // 16B chunks per row
    constexpr int NL = AU + BU;              // per-thread loads per tile
    __shared__ __align__(16) short As[3][BM * BK];
    __shared__ __align__(16) short Bs[3][BN * BK];
    int tid  = threadIdx.x;
    int lane = tid & 63;
    int w    = tid >> 6;

    int nwg = gridDim.x;
    int bid = blockIdx.x;
    int sid = (bid & 7) * (nwg >> 3) + (bid >> 3);
    int row0, n0;
    if (NFAST) { row0 = (sid / gx) * BM; n0 = (sid % gx) * BN; }
    else       { row0 = (sid % gx) * BM; n0 = (sid / gx) * BN; }

    int which = n0 / nper;
    int ncol0 = n0 - which * nper;
    const float* Bv = (which == 0) ? Bb0 : ((which == 1) ? Bb1 : Bb2);
    float alpha = (which == 0) ? alpha0 : 1.0f;

    int wr = (w >> 1) * (BM / 2);
    int wc = (w & 1) * (BN / 2);
    int fr = lane & 15;
    int q4 = lane >> 4;          // 0..3

    auto swz = [&](int r) -> int { return (BK == 64) ? (r & 7) : ((r >> 1) & 3); };

    f32x4 acc[MR][NR] = {};

    auto stageA = [&](int buf, int k0) {
        #pragma unroll
        for (int ii = 0; ii < AU; ++ii) {
            int U = ii * 256 + tid;          // 16B unit
            int r = U / CH;
            int ch = (U % CH) ^ swz(r);
            gload16(A + (size_t)(row0 + r) * K + k0 + ch * 8,
                    (char*)&As[buf][0] + ((size_t)ii * 256 + w * 64) * 16);
        }
    };
    auto stageB = [&](int buf, int k0) {
        #pragma unroll
        for (int ii = 0; ii < BU; ++ii) {
            int U = ii * 256 + tid;
            int r = U / CH;
            int ch = (U % CH) ^ swz(r);
            gload16(Wt + (size_t)(n0 + r) * K + k0 + ch * 8,
                    (char*)&Bs[buf][0] + ((size_t)ii * 256 + w * 64) * 16);
        }
    };
    auto compute = [&](int buf) {
        #pragma unroll
        for (int s = 0; s < SUBK; ++s) {
            bf16x8 af[MR], bfr[NR];
            #pragma unroll
            for (int m = 0; m < MR; ++m) {
                int r = wr + m * 16 + fr;
                af[m] = *(const bf16x8*)((const char*)&As[buf][0]
                        + (size_t)r * (2 * BK) + (((q4 + 4 * s) ^ swz(r)) * 16));
            }
            #pragma unroll
            for (int n = 0; n < NR; ++n) {
                int r = wc + n * 16 + fr;
                bfr[n] = *(const bf16x8*)((const char*)&Bs[buf][0]
                        + (size_t)r * (2 * BK) + (((q4 + 4 * s) ^ swz(r)) * 16));
            }
            #pragma unroll
            for (int m = 0; m < MR; ++m)
                #pragma unroll
                for (int n = 0; n < NR; ++n)
                    acc[m][n] = __builtin_amdgcn_mfma_f32_16x16x32_bf16(af[m], bfr[n], acc[m][n], 0, 0, 0);
        }
    };

    int nt = K / BK;
    stageA(0, 0); stageB(0, 0);
    stageA(1, BK); stageB(1, BK);
    for (int t = 0; t < nt - 1; ++t) {
        asm volatile("s_waitcnt vmcnt(%0)" :: "i"(NL) : "memory");   // tile t landed
        __builtin_amdgcn_sched_barrier(0);
        __builtin_amdgcn_s_barrier();
        if (t + 2 < nt) {
            int b2 = (t + 2) % 3;
            stageA(b2, (t + 2) * BK);
            stageB(b2, (t + 2) * BK);
        }
        compute(t % 3);
    }
    asm volatile("s_waitcnt vmcnt(0)" ::: "memory");
    __builtin_amdgcn_sched_barrier(0);
    __builtin_amdgcn_s_barrier();
    compute((nt - 1) % 3);

    int rr = q4 * 4;
    if (mode == 1) {
        short* base = outB + (size_t)which * ROWS * D;
        #pragma unroll
        for (int m = 0; m < MR; ++m) {
            int rowb = row0 + wr + m * 16 + rr;
            int b2 = rowb >> 9, s0 = rowb & 511;
            #pragma unroll
            for (int n = 0; n < NR; ++n) {
                int col = ncol0 + wc + n * 16 + fr;
                int h2 = col >> 6, d2 = col & 63;
                float bv = Bv[col];
                if (which == 2) {
                    bf16x4 pk;
                    #pragma unroll
                    for (int ri = 0; ri < 4; ++ri) pk[ri] = f2b(acc[m][n][ri] + bv);
                    *(bf16x4*)&base[(((size_t)b2 * H + h2) * 64 + d2) * 512 + s0] = pk;
                } else {
                    #pragma unroll
                    for (int ri = 0; ri < 4; ++ri)
                        base[(((size_t)b2 * H + h2) * 512 + (s0 + ri)) * 64 + d2] =
                            f2b((acc[m][n][ri] + bv) * alpha);
                }
            }
        }
        return;
    }

    #pragma unroll
    for (int m = 0; m < MR; ++m) {
        #pragma unroll
        for (int n = 0; n < NR; ++n) {
            int col  = ncol0 + wc + n * 16 + fr;
            float bv = Bv[col];
            #pragma unroll
            for (int ri = 0; ri < 4; ++ri) {
                int row = row0 + wr + m * 16 + rr + ri;
                size_t idx = (size_t)row * nper + col;
                float val = acc[m][n][ri] + bv;
                if (mode == 2) {
                    outB[idx] = f2b(gelu_f(val));
                } else {
                    outF[idx] = val + resid[idx];
                }
            }
        }
    }
}

// ---------------------------------------------------------------------------
// LDS-staged online-softmax attention, KV j-tile = 64 (32KB LDS -> all 768
// blocks co-resident). Round-10 sync structure, 8 tiles. No setprio.
// ---------------------------------------------------------------------------
__global__ __launch_bounds__(256) void attn_kernel(
    const short* __restrict__ qb, const short* __restrict__ kbuf,
    const short* __restrict__ vtb,
    const uint32_t* __restrict__ pb,
    const float* __restrict__ vd, const float* __restrict__ ac,
    short* __restrict__ o)
{
    __shared__ __align__(16) short Ks[2][64 * 64];   // 8KB each: [j-row][d]
    __shared__ __align__(16) short Vs[2][64 * 64];   // 8KB each: [d][j]
    int tid = threadIdx.x, lane = tid & 63, w = tid >> 6;
    int bid = blockIdx.x;
    int b    = bid & 7;
    int qblk = (bid >> 3) & 7;
    int hh   = bid >> 6;
    int fr = lane & 15, g16 = lane >> 4;
    int kb8 = g16 * 8, rr = g16 * 4;
    int i0 = qblk * 64 + w * 16;
    int i  = i0 + fr;

    const short* qp = qb   + ((size_t)(b * H + hh) * S) * 64;
    const short* kp = kbuf + ((size_t)(b * H + hh) * S) * 64;
    const short* vp = vtb  + ((size_t)(b * H + hh) * 64) * S;

    bf16x8 aq0 = *(const bf16x8*)&qp[(i0 + fr) * 64 + kb8];
    bf16x8 aq1 = *(const bf16x8*)&qp[(i0 + fr) * 64 + 32 + kb8];

    float Ah = ac[hh], Ch = ac[16 + hh], th = vd[hh];
    const uint32_t* pbb = pb + (size_t)b * S * S + (size_t)i * S;

    auto stageK = [&](int buf, int j0) {
        #pragma unroll
        for (int ii = 0; ii < 2; ++ii) {
            int U = ii * 256 + tid;
            int r = U >> 3;
            int ch = (U & 7) ^ (r & 7);
            gload16(kp + (size_t)(j0 + r) * 64 + ch * 8,
                    (char*)&Ks[buf][0] + ((size_t)ii * 256 + w * 64) * 16);
        }
    };
    auto stageV = [&](int buf, int j0) {
        #pragma unroll
        for (int ii = 0; ii < 2; ++ii) {
            int U = ii * 256 + tid;
            int d = U >> 3;
            int s8 = (2 * (U & 7)) ^ (d & 14);
            gload16(vp + (size_t)d * S + j0 + s8 * 4,
                    (char*)&Vs[buf][0] + ((size_t)ii * 256 + w * 64) * 16);
        }
    };

    float m_run = -3.0e38f, l_run = 0.f;
    f32x4 oacc[4] = {};

    stageK(0, 0);
    stageV(0, 0);
    __syncthreads();
    int buf = 0;
    #pragma unroll 1
    for (int t = 0; t < 8; ++t) {
        if (t < 7) { stageK(buf ^ 1, (t + 1) * 64); stageV(buf ^ 1, (t + 1) * 64); }
        f32x4 s[4];
        #pragma unroll
        for (int jt = 0; jt < 4; ++jt) {
            int jb = t * 4 + jt;
            u32x4 u = *(const u32x4*)&pbb[jb * 16 + rr];
            f32x4 c;
            #pragma unroll
            for (int ri = 0; ri < 4; ++ri) {
                int j = jb * 16 + rr + ri;
                float bias = b2f_lo(u[ri]);
                if (i > 0 && j > 0) bias += b2f_hi(u[ri]) * Ah + Ch;
                if (i == 0 || j == 0) bias += th;
                c[ri] = bias;
            }
            int r = jt * 16 + fr;
            const char* krow = (const char*)&Ks[buf][0] + r * 128;
            bf16x8 kf0 = *(const bf16x8*)(krow + ((g16 ^ (r & 7)) * 16));
            bf16x8 kf1 = *(const bf16x8*)(krow + (((g16 + 4) ^ (r & 7)) * 16));
            c = __builtin_amdgcn_mfma_f32_16x16x32_bf16(kf0, aq0, c, 0, 0, 0);
            s[jt] = __builtin_amdgcn_mfma_f32_16x16x32_bf16(kf1, aq1, c, 0, 0, 0);
        }
        float tm = s[0][0];
        #pragma unroll
        for (int jt = 0; jt < 4; ++jt)
            #pragma unroll
            for (int ri = 0; ri < 4; ++ri) tm = fmaxf(tm, s[jt][ri]);
        tm = fmaxf(tm, __shfl_xor(tm, 16));
        tm = fmaxf(tm, __shfl_xor(tm, 32));
        float mnew = fmaxf(m_run, tm);
        float scale = __expf(m_run - mnew);
        l_run *= scale;
        #pragma unroll
        for (int ri = 0; ri < 4; ++ri) {
            float scr = __shfl(scale, rr + ri);
            #pragma unroll
            for (int dt = 0; dt < 4; ++dt) oacc[dt][ri] *= scr;
        }
        #pragma unroll
        for (int jt = 0; jt < 4; ++jt)
            #pragma unroll
            for (int ri = 0; ri < 4; ++ri) {
                float p = __expf(s[jt][ri] - mnew);
                s[jt][ri] = p;
                l_run += p;
            }
        #pragma unroll
        for (int jt = 0; jt < 4; ++jt) {
            bf16x4 pa;
            #pragma unroll
            for (int ri = 0; ri < 4; ++ri) pa[ri] = f2b(s[jt][ri]);
            #pragma unroll
            for (int dt = 0; dt < 4; ++dt) {
                int d = dt * 16 + fr;
                const char* vrow = (const char*)&Vs[buf][0] + d * 128;
                bf16x4 vb = *(const bf16x4*)(vrow + (((jt * 4 + g16) ^ (d & 14)) * 8));
                oacc[dt] = mfma16(pa, vb, oacc[dt]);
            }
        }
        m_run = mnew;
        __syncthreads();
        buf ^= 1;
    }
    mfma16_fence(oacc);

    l_run += __shfl_xor(l_run, 16);
    l_run += __shfl_xor(l_run, 32);
    float invl = 1.f / l_run;
    #pragma unroll
    for (int ri = 0; ri < 4; ++ri) {
        float ivr = __shfl(invl, rr + ri);
        #pragma unroll
        for (int dt = 0; dt < 4; ++dt)
            o[((size_t)(b * S + i0 + rr + ri) * H + hh) * 64 + dt * 16 + fr] =
                f2b(oacc[dt][ri] * ivr);
    }
}

// ---------------------------------------------------------------------------
extern "C" void kernel_launch(void* const* d_in, const int* in_sizes, int n_in,
                              void* d_out, int out_size, void* d_ws, size_t ws_size,
                              hipStream_t stream)
{
    const float* attn_bias   = (const float*)d_in[0];
    const float* spatial_pos = (const float*)d_in[1];
    const int*   xx          = (const int*)d_in[2];
    const float* node_emb    = (const float*)d_in[3];
    const float* graph_token = (const float*)d_in[4];
    const float* virt_dist   = (const float*)d_in[5];
    const float* sp_w1 = (const float*)d_in[6];
    const float* sp_b1 = (const float*)d_in[7];
    const float* sp_w2 = (const float*)d_in[8];
    const float* sp_b2 = (const float*)d_in[9];
    const float* ln1_s = (const float*)d_in[10];
    const float* ln1_b = (const float*)d_in[11];
    const float* wq = (const float*)d_in[12];
    const float* bq = (const float*)d_in[13];
    const float* wk = (const float*)d_in[14];
    const float* bk = (const float*)d_in[15];
    const float* wv = (const float*)d_in[16];
    const float* bv = (const float*)d_in[17];
    const float* wo = (const float*)d_in[18];
    const float* bo = (const float*)d_in[19];
    const float* ln2_s = (const float*)d_in[20];
    const float* ln2_b = (const float*)d_in[21];
    const float* fw1 = (const float*)d_in[22];
    const float* fb1 = (const float*)d_in[23];
    const float* fw2 = (const float*)d_in[24];
    const float* fb2 = (const float*)d_in[25];
    const float* fln_s = (const float*)d_in[26];
    const float* fln_b = (const float*)d_in[27];

    float* wsf = (float*)d_ws;
    const size_t SZ = (size_t)ROWS * D;        // 3,145,728
    float* h   = wsf;                          // f32 [ROWS][D]
    float* acb = wsf + SZ;                     // A[12],C[12]
    short* s16 = (short*)(wsf + SZ + 64);
    short* yob = s16;                          // bf16 [ROWS][D]
    short* g16b = s16 + SZ;                    // bf16 [ROWS][FFN]
    short* bfq = g16b + (size_t)ROWS * FFN;    // 3 x bf16 [ROWS*D]
    short* wqkvT = bfq + 3 * SZ;               // [2304][768]
    short* woT   = wqkvT + 2304 * 768;         // [768][768]
    short* f1T   = woT + 768 * 768;            // [3072][768]
    short* f2T   = f1T + (size_t)3072 * 768;   // [768][3072]
    uint32_t* pbias = (uint32_t*)(f2T + (size_t)768 * 3072);  // [B][S][S] u32

    embed_kernel<<<ROWS, 256, 0, stream>>>(xx, node_emb, graph_token, h);
    ac_kernel<<<1, 64, 0, stream>>>(sp_w1, sp_b1, sp_w2, sp_b2, acb);
    bias_pack_kernel<<<ROWS, 256, 0, stream>>>(attn_bias, spatial_pos, pbias);

    for (int l = 0; l < 6; ++l) {
        wcvt_kernel<<<1728, 256, 0, stream>>>(
            wq + (size_t)l * D * D, wk + (size_t)l * D * D, wv + (size_t)l * D * D,
            wo + (size_t)l * D * D, fw1 + (size_t)l * D * FFN, fw2 + (size_t)l * FFN * D,
            wqkvT, woT, f1T, f2T);
        ln_kernel<<<ROWS, 256, 0, stream>>>(h, ln1_s + l * D, ln1_b + l * D, nullptr, yob);
        // QKV: 128x128/BK=32, M-fastest; 576 blocks
        gemm2<128, 128, 32, false><<<576, 256, 0, stream>>>(
            yob, wqkvT, bq + l * D, bk + l * D, bv + l * D,
            nullptr, nullptr, bfq, D, D, 32, 0.125f, 1);
        attn_kernel<<<B * H * 8, 256, 0, stream>>>(
            bfq, bfq + SZ, bfq + 2 * SZ, pbias, virt_dist, acb, yob);
        // o-proj: 64x64/BK=64, N-fastest; 768 blocks
        gemm2<64, 64, 64, true><<<768, 256, 0, stream>>>(
            yob, woT, bo + l * D, nullptr, nullptr,
            h, h, nullptr, D, D, 12, 1.0f, 0);
        ln_kernel<<<ROWS, 256, 0, stream>>>(h, ln2_s + l * D, ln2_b + l * D, nullptr, yob);
        // FFN1: 128x128/BK=32, M-fastest; 768 blocks
        gemm2<128, 128, 32, false><<<768, 256, 0, stream>>>(
            yob, f1T, fb1 + l * FFN, nullptr, nullptr,
            nullptr, nullptr, g16b, D, FFN, 32, 1.0f, 2);
        // FFN2: 64x64/BK=64, N-fastest; 768 blocks
        gemm2<64, 64, 64, true><<<768, 256, 0, stream>>>(
            g16b, f2T, fb2 + l * D, nullptr, nullptr,
            h, h, nullptr, FFN, D, 12, 1.0f, 0);
    }
    ln_kernel<<<ROWS, 256, 0, stream>>>(h, fln_s, fln_b, (float*)d_out, nullptr);
}